// Round 4
// baseline (1864.042 us; speedup 1.0000x reference)
//
#include <hip/hip_runtime.h>
#include <stdint.h>

// Problem constants
#define NPTS 400000
#define DIM  128
#define KNB  27
#define NSEG 8

typedef _Float16 f16x8 __attribute__((ext_vector_type(8)));
typedef float floatx16 __attribute__((ext_vector_type(16)));

// Workspace layout (bytes). Total ~309 MB + 288 B.
#define OFF_FEATSH 0UL                    // N*128 f16 = 102,400,000
#define OFF_OUT1   102400000UL            // N*128 f16
#define OFF_OUT2   204800000UL            // N*128 f16
#define OFF_PW1    307200000UL            // 27*128*128 f16 = 884,736
#define OFF_PW2    308084736UL
#define OFF_PW3    308969472UL            // 128*128 f16 = 32,768
#define OFF_SEG    309002240UL            // 8*128 f32 = 4096
#define OFF_CNT    309006336UL            // 8 f32 = 32
#define OFF_ZROW   309006368UL            // 256 B zeroed feature row (masked-gather target)
#define ZOFF       309006368              // byte offset of zero row from featsh base

#define LDS_W_OFF  65536                  // W buffer (64KB, single) after A (64KB)

__device__ __forceinline__ void load_lds16(const void* g, void* l) {
  __builtin_amdgcn_global_load_lds(
      (const __attribute__((address_space(1))) void*)g,
      (__attribute__((address_space(3))) void*)l, 16, 0, 0);
}

// ---------------- feats fp32 -> f16 ----------------
__global__ __launch_bounds__(256) void cvt_feats(const float* __restrict__ f,
                                                 _Float16* __restrict__ fh) {
  size_t g = (size_t)blockIdx.x * 256 + threadIdx.x;   // 6,400,000 threads, 8 elems each
  const float4* src = (const float4*)f;
  float4 v0 = src[g * 2], v1 = src[g * 2 + 1];
  f16x8 o;
  o[0] = (_Float16)v0.x; o[1] = (_Float16)v0.y; o[2] = (_Float16)v0.z; o[3] = (_Float16)v0.w;
  o[4] = (_Float16)v1.x; o[5] = (_Float16)v1.y; o[6] = (_Float16)v1.z; o[7] = (_Float16)v1.w;
  ((f16x8*)fh)[g] = o;
}

// ---------------- pack W1/W2/W3 into B-fragment order ----------------
// B frag for mfma_f32_32x32x16_f16: lane holds 8 f16: B[kk][c], c = ct*32+(lane&31),
// kk = ko*16 + (lane>>5)*8 + j. Packed flat: [k][ko][ct][lane][8].
__global__ __launch_bounds__(256) void pack_w(const float* __restrict__ W1,
                                              const float* __restrict__ W2,
                                              const float* __restrict__ W3,
                                              _Float16* __restrict__ pW1,
                                              _Float16* __restrict__ pW2,
                                              _Float16* __restrict__ pW3) {
  int gid = blockIdx.x * 256 + threadIdx.x;            // 112,640 total
  const float* W; _Float16* dst; int k, rem;
  if (gid < 110592) {
    int mat = gid / 55296, r = gid % 55296;
    W = mat ? W2 : W1; dst = (mat ? pW2 : pW1) + (size_t)r * 8;
    k = r >> 11; rem = r & 2047;
  } else {
    int r = gid - 110592;                              // 0..2047
    W = W3; dst = pW3 + (size_t)r * 8; k = 0; rem = r;
  }
  int ko = rem >> 8, ct = (rem >> 6) & 3, lane = rem & 63;
  int h = lane >> 5, c = ct * 32 + (lane & 31);
  f16x8 o;
#pragma unroll
  for (int j = 0; j < 8; ++j) {
    int kk = ko * 16 + h * 8 + j;
    o[j] = (_Float16)W[(size_t)(k * 128 + kk) * 128 + c];
  }
  *(f16x8*)dst = o;
}

// ---------------- conv kernel: 256 rows/block, 2 row-tiles/wave, swizzled A ----------------
// Block = 512 thr (8 waves) = 256 rows, both convs. Wave ws: conv = ws>>2, owns rows
// [(ws&3)*64, +64) as 2 row-tiles (acc0/acc1: one B ds_read feeds 2 MFMAs -> B LDS
// traffic per MFMA halved vs R3). W staged ONCE per 256 rows (amortization 2x vs R3).
// A LDS layout XOR-swizzled: byte = chunk*4096 + ((row^chunk))*16, chunk=byte16 idx
// (0..15) -> ds_write of 4 consecutive lanes (chunks c..c+3, same row) hits 4 distinct
// banks (R3 had 4-way conflicts, 67M cycles); reads stay contiguous-per-halfwave (free).
// LDS: A 64KB + W 64KB single buffer = 128KB (1 block/CU, 2 waves/SIMD).
// Pipeline: gathers A(k+1)+idx(k+2) issued at top of compute(k) (TA churns under MFMA);
// after BarrierA: ds_write A(k+1), stage W(k+1), lgkm+vmcnt drain (only ops issued
// moments before; nothing long-lived killed), BarrierB.
__global__ __launch_bounds__(512, 2) void conv_kernel(
    const _Float16* __restrict__ featsh, const int* __restrict__ nidx,
    const int* __restrict__ nmask, const int* __restrict__ segids,
    const _Float16* __restrict__ pW1, const _Float16* __restrict__ pW2,
    const float* __restrict__ b1, const float* __restrict__ b2,
    _Float16* __restrict__ out1, _Float16* __restrict__ out2,
    float* __restrict__ seg_sums, float* __restrict__ cnts_f) {
  __shared__ __align__(16) char lds_raw[131072];  // [0,64K): A swz; [64K,128K): W
  int tid = threadIdx.x, ws = tid >> 6, lane = tid & 63, h = lane >> 5;
  int conv = ws >> 2;
  int n0 = blockIdx.x * 256;                      // grid 1563; tail block has 128 rows
  int jlane = lane & 3;                           // 16B sub-chunk within 64B
  int srowA = ws * 32 + (lane >> 2);              // staging rows (4 lanes x 16B = 64B line)
  int srowB = srowA + 16;
  int growA = n0 + srowA, growB = n0 + srowB;
  bool vA = growA < NPTS, vB = growB < NPTS;
  size_t gxA = (size_t)(vA ? growA : NPTS - 1) * KNB;
  size_t gxB = (size_t)(vB ? growB : NPTS - 1) * KNB;
  int r0 = (ws & 3) * 64 + (lane & 31);           // compute row-tile rows (block-local)
  int r1 = r0 + 32;

  const char* fb = (const char*)featsh;           // zero row at byte ZOFF
  const char* srcW = (const char*)(ws < 4 ? pW1 : pW2) + (size_t)(ws & 3) * 8192;
  char* wdst = lds_raw + LDS_W_OFF + (conv ? 32768 : 0) + (ws & 3) * 8192;

  floatx16 acc0[4], acc1[4];
#pragma unroll
  for (int ct = 0; ct < 4; ++ct)
#pragma unroll
    for (int r = 0; r < 16; ++r) { acc0[ct][r] = 0.f; acc1[ct][r] = 0.f; }

  uint4 agA[4], agB[4];
  int iN_A, mN_A, iN_B, mN_B;

  // ---- prologue: idx(0), gather A(0), stage W(0), idx(1), ds_write A(0), drain ----
  {
    int iA = nidx[gxA], mA = vA ? nmask[gxA] : 0;
    int iB = nidx[gxB], mB = vB ? nmask[gxB] : 0;
    int offA = mA ? iA * 256 : ZOFF;
    int offB = mB ? iB * 256 : ZOFF;
#pragma unroll
    for (int q = 0; q < 4; ++q) {
      agA[q] = *(const uint4*)(fb + offA + q * 64 + jlane * 16);
      agB[q] = *(const uint4*)(fb + offB + q * 64 + jlane * 16);
    }
#pragma unroll
    for (int it = 0; it < 8; ++it)
      load_lds16(srcW + it * 1024 + lane * 16, wdst + it * 1024);
    iN_A = nidx[gxA + 1]; mN_A = vA ? nmask[gxA + 1] : 0;
    iN_B = nidx[gxB + 1]; mN_B = vB ? nmask[gxB + 1] : 0;
#pragma unroll
    for (int q = 0; q < 4; ++q) {
      int cA = q * 4 + jlane;
      *(uint4*)(lds_raw + cA * 4096 + (srowA ^ cA) * 16) = agA[q];
      *(uint4*)(lds_raw + cA * 4096 + (srowB ^ cA) * 16) = agB[q];
    }
    __syncthreads();
  }

  for (int k = 0; k < KNB; ++k) {
    // [top-of-compute prefetch issues: processed by TA while SIMDs run MFMA]
    int offA = mN_A ? iN_A * 256 : ZOFF;          // waits last iter's idx loads only
    int offB = mN_B ? iN_B * 256 : ZOFF;
    __builtin_amdgcn_sched_barrier(0);
#pragma unroll
    for (int q = 0; q < 4; ++q) {                 // gather A(k+1) -> regs (8 x dwordx4)
      agA[q] = *(const uint4*)(fb + offA + q * 64 + jlane * 16);
      agB[q] = *(const uint4*)(fb + offB + q * 64 + jlane * 16);
    }
    __builtin_amdgcn_sched_barrier(0);
    {                                             // idx/mask(k+2)
      int kq = (k + 2 <= KNB - 1) ? k + 2 : KNB - 1;
      iN_A = nidx[gxA + kq]; mN_A = vA ? nmask[gxA + kq] : 0;
      iN_B = nidx[gxB + kq]; mN_B = vB ? nmask[gxB + kq] : 0;
    }
    __builtin_amdgcn_sched_barrier(0);

    // compute(k): A from swizzled LDS, B from W buffer; B read once -> 2 MFMAs
    const _Float16* ldsW = (const _Float16*)(lds_raw + LDS_W_OFF + conv * 32768);
#pragma unroll
    for (int ko = 0; ko < 8; ++ko) {
      int c0 = ko * 2 + h;
      f16x8 a0 = *(const f16x8*)(lds_raw + c0 * 4096 + (r0 ^ c0) * 16);
      f16x8 a1 = *(const f16x8*)(lds_raw + c0 * 4096 + (r1 ^ c0) * 16);
#pragma unroll
      for (int ct = 0; ct < 4; ++ct) {
        f16x8 b = *(const f16x8*)(ldsW + ((ko * 4 + ct) * 64 + lane) * 8);
        acc0[ct] = __builtin_amdgcn_mfma_f32_32x32x16_f16(a0, b, acc0[ct], 0, 0, 0);
        acc1[ct] = __builtin_amdgcn_mfma_f32_32x32x16_f16(a1, b, acc1[ct], 0, 0, 0);
      }
    }
    __builtin_amdgcn_sched_barrier(0);
    __builtin_amdgcn_s_barrier();                 // BarrierA: all reads of A(k)/W(k) done
    __builtin_amdgcn_sched_barrier(0);

    // write A(k+1) (compiler waits the 8 gathers -- issued a full compute phase ago)
#pragma unroll
    for (int q = 0; q < 4; ++q) {
      int cA = q * 4 + jlane;
      *(uint4*)(lds_raw + cA * 4096 + (srowA ^ cA) * 16) = agA[q];
      *(uint4*)(lds_raw + cA * 4096 + (srowB ^ cA) * 16) = agB[q];
    }
    {                                             // stage W(k+1) (single buffer)
      int ks = (k + 1 <= KNB - 1) ? k + 1 : KNB - 1;
      const char* sk = srcW + (size_t)ks * 32768;
#pragma unroll
      for (int it = 0; it < 8; ++it)
        load_lds16(sk + it * 1024 + lane * 16, wdst + it * 1024);
    }
    __builtin_amdgcn_sched_barrier(0);
    asm volatile("s_waitcnt lgkmcnt(0)" ::: "memory");   // A writes visible
    asm volatile("s_waitcnt vmcnt(0)" ::: "memory");     // W(k+1) landed (newest ops)
    __builtin_amdgcn_sched_barrier(0);
    __builtin_amdgcn_s_barrier();                 // BarrierB: A(k+1)/W(k+1) ready
    __builtin_amdgcn_sched_barrier(0);
  }

  // ---- epilogue: bias + relu ----
  const float* bb = conv ? b2 : b1;
  float bias[4];
#pragma unroll
  for (int ct = 0; ct < 4; ++ct) bias[ct] = bb[ct * 32 + (lane & 31)];
#pragma unroll
  for (int ct = 0; ct < 4; ++ct)
#pragma unroll
    for (int r = 0; r < 16; ++r) {
      acc0[ct][r] = fmaxf(acc0[ct][r] + bias[ct], 0.f);
      acc1[ct][r] = fmaxf(acc1[ct][r] + bias[ct], 0.f);
    }

  int nvalid = (NPTS - n0 < 256) ? (NPTS - n0) : 256;
  int seg0 = segids[n0];
  bool uniform = (nvalid == 256) && (seg0 == segids[n0 + 255]);  // sorted segment_ids

  // segment column sums of out2 (uniform fast path: per-wave shuffle reduce + atomics)
  if (conv == 1 && uniform) {
#pragma unroll
    for (int ct = 0; ct < 4; ++ct) {
      float s = 0.f;
#pragma unroll
      for (int r = 0; r < 16; ++r) s += acc0[ct][r] + acc1[ct][r];
      s += __shfl_xor(s, 32);                     // combine h halves -> 64-row col sum
      if (lane < 32) atomicAdd(&seg_sums[seg0 * 128 + ct * 32 + lane], s);
    }
  }
  if (tid == 0 && uniform) atomicAdd(&cnts_f[seg0], 256.0f);

  __syncthreads();                                // full drain (incl. stray clamped stage)
  // transpose C-layout accs -> row-major f16 in LDS [2][256][128] = 128KB (reuses all)
  _Float16* lds_out = (_Float16*)lds_raw;
#pragma unroll
  for (int ct = 0; ct < 4; ++ct) {
    int col = ct * 32 + (lane & 31);
#pragma unroll
    for (int r = 0; r < 16; ++r) {
      int lr = (ws & 3) * 64 + (r & 3) + 8 * (r >> 2) + 4 * h;  // C/D row map (m74/m101)
      lds_out[conv * 32768 + lr * 128 + col] = (_Float16)acc0[ct][r];
      lds_out[conv * 32768 + (lr + 32) * 128 + col] = (_Float16)acc1[ct][r];
    }
  }
  __syncthreads();

  if (!uniform && tid < 256) {                    // boundary/tail blocks: per-row atomics
    if (n0 + tid < NPTS) {
      int s = segids[n0 + tid];
      atomicAdd(&cnts_f[s], 1.0f);
      for (int c = 0; c < 128; ++c)
        atomicAdd(&seg_sums[s * 128 + c], (float)lds_out[32768 + tid * 128 + c]);
    }
  }

  // coalesced row-major stores of out1/out2 (128KB total)
#pragma unroll
  for (int it = 0; it < 16; ++it) {
    int chunk = it * 512 + tid;                   // 0..8191, 16B each
    int cv = chunk >> 12;
    int off16 = chunk & 4095;
    if (n0 + (off16 >> 4) < NPTS) {
      uint4 v = *(const uint4*)(lds_raw + cv * 65536 + off16 * 16);
      *(uint4*)((cv ? out2 : out1) + (size_t)n0 * 128 + (size_t)off16 * 8) = v;
    }
  }
}

// ---------------- final kernel: enc/mid + mid@W3 + relu(feats - relu(.)) ----------------
__global__ __launch_bounds__(256, 2) void final_kernel(
    const float* __restrict__ feats, const _Float16* __restrict__ out1,
    const _Float16* __restrict__ out2, const int* __restrict__ segids,
    const float* __restrict__ seg_sums, const float* __restrict__ cnts_f,
    const char* __restrict__ pW3, const float* __restrict__ b3,
    float* __restrict__ dout) {
  __shared__ __align__(16) char ldsw3[32768];
  __shared__ float smean[NSEG * 128];
  int tid = threadIdx.x, w = tid >> 6, lane = tid & 63, h = lane >> 5;
  int n0 = blockIdx.x * 128;
#pragma unroll
  for (int it = 0; it < 8; ++it)
    load_lds16(pW3 + w * 8192 + it * 1024 + lane * 16, ldsw3 + w * 8192 + it * 1024);
  for (int i = tid; i < NSEG * 128; i += 256)
    smean[i] = seg_sums[i] / fmaxf(cnts_f[i >> 7], 1.0f);
  __syncthreads();

  int row = n0 + w * 32 + (lane & 31);
  int seg = segids[row];
  const char* p1 = (const char*)(out1 + (size_t)row * 128 + h * 8);
  const char* p2 = (const char*)(out2 + (size_t)row * 128 + h * 8);
  f16x8 o1[8], o2[8];
  float s1 = 0.f;
#pragma unroll
  for (int ko = 0; ko < 8; ++ko) {
    o1[ko] = *(const f16x8*)(p1 + ko * 32);
    o2[ko] = *(const f16x8*)(p2 + ko * 32);
#pragma unroll
    for (int j = 0; j < 8; ++j) s1 += (float)o1[ko][j];
  }
  s1 += __shfl_xor(s1, 32);
  float rm = s1 * (1.0f / 128.0f);             // row mean of out1 (out1 >= 0)

  f16x8 a[8];
#pragma unroll
  for (int ko = 0; ko < 8; ++ko) {
    int colb = ko * 16 + h * 8;
#pragma unroll
    for (int j = 0; j < 8; ++j) {
      float m2 = smean[seg * 128 + colb + j];
      float e = sqrtf(fmaf(rm, m2, 1e-12f));
      a[ko][j] = (_Float16)(e + (float)o1[ko][j] + (float)o2[ko][j]);
    }
  }
  floatx16 acc[4];
#pragma unroll
  for (int ct = 0; ct < 4; ++ct)
#pragma unroll
    for (int r = 0; r < 16; ++r) acc[ct][r] = 0.f;
#pragma unroll
  for (int ko = 0; ko < 8; ++ko)
#pragma unroll
    for (int ct = 0; ct < 4; ++ct) {
      f16x8 b = *(const f16x8*)(ldsw3 + ((ko * 4 + ct) * 64 + lane) * 16);
      acc[ct] = __builtin_amdgcn_mfma_f32_32x32x16_f16(a[ko], b, acc[ct], 0, 0, 0);
    }
#pragma unroll
  for (int ct = 0; ct < 4; ++ct) {
    int col = ct * 32 + (lane & 31);
    float bc = b3[col];
#pragma unroll
    for (int r = 0; r < 16; ++r) {
      int gr = n0 + w * 32 + (r & 3) + 8 * (r >> 2) + 4 * h;
      float v = fmaxf(acc[ct][r] + bc, 0.f);
      float f = feats[(size_t)gr * 128 + col];
      dout[(size_t)gr * 128 + col] = fmaxf(f - v, 0.f);
    }
  }
}

extern "C" void kernel_launch(void* const* d_in, const int* in_sizes, int n_in,
                              void* d_out, int out_size, void* d_ws, size_t ws_size,
                              hipStream_t stream) {
  (void)in_sizes; (void)n_in; (void)out_size; (void)ws_size;
  const float* feats = (const float*)d_in[0];
  const int* nidx   = (const int*)d_in[1];
  const int* nmask  = (const int*)d_in[2];   // bool mask; int32 per harness convention
  const int* segids = (const int*)d_in[3];
  const float* W1 = (const float*)d_in[5];
  const float* b1 = (const float*)d_in[6];
  const float* W2 = (const float*)d_in[7];
  const float* b2 = (const float*)d_in[8];
  const float* W3 = (const float*)d_in[9];
  const float* b3 = (const float*)d_in[10];
  float* dout = (float*)d_out;
  char* ws = (char*)d_ws;

  _Float16* featsh = (_Float16*)(ws + OFF_FEATSH);
  _Float16* out1h  = (_Float16*)(ws + OFF_OUT1);
  _Float16* out2h  = (_Float16*)(ws + OFF_OUT2);
  _Float16* pW1    = (_Float16*)(ws + OFF_PW1);
  _Float16* pW2    = (_Float16*)(ws + OFF_PW2);
  _Float16* pW3    = (_Float16*)(ws + OFF_PW3);
  float* seg_sums  = (float*)(ws + OFF_SEG);
  float* cnts_f    = (float*)(ws + OFF_CNT);

  // zero seg sums + counts + the masked-gather zero row (contiguous)
  hipMemsetAsync(ws + OFF_SEG, 0, 4096 + 32 + 256, stream);
  cvt_feats<<<25000, 256, 0, stream>>>(feats, featsh);
  pack_w<<<440, 256, 0, stream>>>(W1, W2, W3, pW1, pW2, pW3);
  conv_kernel<<<1563, 512, 0, stream>>>(featsh, nidx, nmask, segids, pW1, pW2,
                                        b1, b2, out1h, out2h, seg_sums, cnts_f);
  final_kernel<<<3125, 256, 0, stream>>>(feats, out1h, out2h, segids, seg_sums,
                                         cnts_f, (const char*)pW3, b3, dout);
}

// Round 5
// 1570.276 us; speedup vs baseline: 1.1871x; 1.1871x over previous
//
#include <hip/hip_runtime.h>
#include <stdint.h>

// Problem constants
#define NPTS 400000
#define DIM  128
#define KNB  27
#define NSEG 8

typedef _Float16 f16x8 __attribute__((ext_vector_type(8)));
typedef float floatx16 __attribute__((ext_vector_type(16)));

// Workspace layout (bytes). Total ~309 MB + 288 B.
#define OFF_FEATSH 0UL                    // N*128 f16 = 102,400,000
#define OFF_OUT1   102400000UL            // N*128 f16
#define OFF_OUT2   204800000UL            // N*128 f16
#define OFF_PW1    307200000UL            // 27*128*128 f16 = 884,736
#define OFF_PW2    308084736UL
#define OFF_PW3    308969472UL            // 128*128 f16 = 32,768
#define OFF_SEG    309002240UL            // 8*128 f32 = 4096
#define OFF_CNT    309006336UL            // 8 f32 = 32
#define OFF_ZROW   309006368UL            // 256 B zeroed feature row (masked-gather target)
#define ZOFF       309006368              // byte offset of zero row from featsh base

// conv_kernel LDS map: [0,32K) A swizzled; [32K,96K) W buf0; [96K,160K) W buf1.
#define LDSA       0
#define LDSW       32768

__device__ __forceinline__ void load_lds16(const void* g, void* l) {
  __builtin_amdgcn_global_load_lds(
      (const __attribute__((address_space(1))) void*)g,
      (__attribute__((address_space(3))) void*)l, 16, 0, 0);
}

// ---------------- feats fp32 -> f16 ----------------
__global__ __launch_bounds__(256) void cvt_feats(const float* __restrict__ f,
                                                 _Float16* __restrict__ fh) {
  size_t g = (size_t)blockIdx.x * 256 + threadIdx.x;   // 6,400,000 threads, 8 elems each
  const float4* src = (const float4*)f;
  float4 v0 = src[g * 2], v1 = src[g * 2 + 1];
  f16x8 o;
  o[0] = (_Float16)v0.x; o[1] = (_Float16)v0.y; o[2] = (_Float16)v0.z; o[3] = (_Float16)v0.w;
  o[4] = (_Float16)v1.x; o[5] = (_Float16)v1.y; o[6] = (_Float16)v1.z; o[7] = (_Float16)v1.w;
  ((f16x8*)fh)[g] = o;
}

// ---------------- pack W1/W2/W3 into B-fragment order ----------------
// B frag for mfma_f32_32x32x16_f16: lane holds 8 f16: B[kk][c], c = ct*32+(lane&31),
// kk = ko*16 + (lane>>5)*8 + j. Packed flat: [k][ko][ct][lane][8].
__global__ __launch_bounds__(256) void pack_w(const float* __restrict__ W1,
                                              const float* __restrict__ W2,
                                              const float* __restrict__ W3,
                                              _Float16* __restrict__ pW1,
                                              _Float16* __restrict__ pW2,
                                              _Float16* __restrict__ pW3) {
  int gid = blockIdx.x * 256 + threadIdx.x;            // 112,640 total
  const float* W; _Float16* dst; int k, rem;
  if (gid < 110592) {
    int mat = gid / 55296, r = gid % 55296;
    W = mat ? W2 : W1; dst = (mat ? pW2 : pW1) + (size_t)r * 8;
    k = r >> 11; rem = r & 2047;
  } else {
    int r = gid - 110592;                              // 0..2047
    W = W3; dst = pW3 + (size_t)r * 8; k = 0; rem = r;
  }
  int ko = rem >> 8, ct = (rem >> 6) & 3, lane = rem & 63;
  int h = lane >> 5, c = ct * 32 + (lane & 31);
  f16x8 o;
#pragma unroll
  for (int j = 0; j < 8; ++j) {
    int kk = ko * 16 + h * 8 + j;
    o[j] = (_Float16)W[(size_t)(k * 128 + kk) * 128 + c];
  }
  *(f16x8*)dst = o;
}

// ---------------- conv kernel: ko-split waves, W dbuf, swizzled shared A ----------------
// Block = 512 thr (8 waves) = 128 rows, both convs. Wave ws = c*4 + g*2 + j:
//   c = conv, g = row-half (64 rows as 2 row-tiles -> B ds_read feeds 2 MFMAs),
//   j = ko-half (k-dim split; partner waves' partial accs reduced via LDS at end).
// A staged once per block in LDS (32KB), swizzle slot = row ^ (2*chunk):
//   read (fixed chunk, 32 consecutive rows) and write (2 rows x 4 chunks per 8-lane
//   group) both cover all 8 bank-groups -> conflict-free both sides.
// W double-buffered 2x64KB (exactly 160KiB total LDS). No vmcnt(0) in the loop:
// ds_write A(k+1) waits its gathers, which are YOUNGER than the W(k+1) stage in
// issue order, so the vmcnt ordering drains W implicitly.
__global__ __launch_bounds__(512, 2) void conv_kernel(
    const _Float16* __restrict__ featsh, const int* __restrict__ nidx,
    const int* __restrict__ nmask, const int* __restrict__ segids,
    const _Float16* __restrict__ pW1, const _Float16* __restrict__ pW2,
    const float* __restrict__ b1, const float* __restrict__ b2,
    _Float16* __restrict__ out1, _Float16* __restrict__ out2,
    float* __restrict__ seg_sums, float* __restrict__ cnts_f) {
  __shared__ __align__(16) char lds_raw[163840];
  int tid = threadIdx.x, ws = tid >> 6, lane = tid & 63, h = lane >> 5;
  int c_ = ws >> 2, g = (ws >> 1) & 1, j = ws & 1;
  int n0 = blockIdx.x * 128;                      // 3125*128 = 400,000 exact, no tail
  int srow = tid >> 2, jl = tid & 3;              // staging: 4 lanes x 16B per row
  size_t gx = (size_t)(n0 + srow) * KNB;
  int r0 = g * 64 + (lane & 31), r1 = r0 + 32;    // this wave's 2 row-tiles

  const char* fb = (const char*)featsh;           // zero row at byte ZOFF
  const char* srcW = (const char*)(ws < 4 ? pW1 : pW2) + (size_t)(ws & 3) * 8192;

  floatx16 acc0[4], acc1[4];
#pragma unroll
  for (int ct = 0; ct < 4; ++ct)
#pragma unroll
    for (int r = 0; r < 16; ++r) { acc0[ct][r] = 0.f; acc1[ct][r] = 0.f; }

  uint4 ag[4];
  int i_n, m_n;

  // ---- prologue: idx(0), gather A(0), stage W(0)->buf0, idx(1), write A(0), drain ----
  {
    int i0 = nidx[gx], m0 = nmask[gx];
    int off = m0 ? i0 * 256 : ZOFF;
#pragma unroll
    for (int q = 0; q < 4; ++q)
      ag[q] = *(const uint4*)(fb + off + (q * 4 + jl) * 16);
#pragma unroll
    for (int it = 0; it < 8; ++it)
      load_lds16(srcW + it * 1024 + lane * 16, lds_raw + LDSW + ws * 8192 + it * 1024);
    i_n = nidx[gx + 1]; m_n = nmask[gx + 1];
#pragma unroll
    for (int q = 0; q < 4; ++q) {
      int cA = q * 4 + jl;
      *(uint4*)(lds_raw + cA * 2048 + ((srow ^ (2 * cA)) << 4)) = ag[q];
    }
    __syncthreads();
  }

  for (int k = 0; k < KNB; ++k) {
    // [S] stage W(k+1) -> buf[(k+1)&1] (safe: BarrierB(k-1)/prologue-sync passed)
    {
      int ks = (k + 1 <= KNB - 1) ? k + 1 : KNB - 1;
      const char* sk = srcW + (size_t)ks * 32768;
      char* db = lds_raw + LDSW + ((k + 1) & 1) * 65536 + ws * 8192;
#pragma unroll
      for (int it = 0; it < 8; ++it)
        load_lds16(sk + it * 1024 + lane * 16, db + it * 1024);
    }
    __builtin_amdgcn_sched_barrier(0);
    // [G] gather A(k+1) -> regs (waits idx(k+1), issued last iter)
    {
      int off = m_n ? i_n * 256 : ZOFF;
#pragma unroll
      for (int q = 0; q < 4; ++q)
        ag[q] = *(const uint4*)(fb + off + (q * 4 + jl) * 16);
    }
    __builtin_amdgcn_sched_barrier(0);
    // [I] idx/mask(k+2)
    {
      int kq2 = (k + 2 <= KNB - 1) ? k + 2 : KNB - 1;
      i_n = nidx[gx + kq2]; m_n = nmask[gx + kq2];
    }
    __builtin_amdgcn_sched_barrier(0);
    // [C] compute(k): ko-half j, 2 row-tiles, B from buf[k&1]
    {
      const char* wb = lds_raw + LDSW + (k & 1) * 65536 + c_ * 32768;
#pragma unroll
      for (int kq = 0; kq < 4; ++kq) {
        int ko = j * 4 + kq;
        int c0 = ko * 2 + h;
        f16x8 a0 = *(const f16x8*)(lds_raw + c0 * 2048 + ((r0 ^ (2 * c0)) << 4));
        f16x8 a1 = *(const f16x8*)(lds_raw + c0 * 2048 + ((r1 ^ (2 * c0)) << 4));
#pragma unroll
        for (int ct = 0; ct < 4; ++ct) {
          f16x8 b = *(const f16x8*)(wb + ((ko * 4 + ct) * 64 + lane) * 16);
          acc0[ct] = __builtin_amdgcn_mfma_f32_32x32x16_f16(a0, b, acc0[ct], 0, 0, 0);
          acc1[ct] = __builtin_amdgcn_mfma_f32_32x32x16_f16(a1, b, acc1[ct], 0, 0, 0);
        }
      }
    }
    __builtin_amdgcn_sched_barrier(0);
    __builtin_amdgcn_s_barrier();                 // BarrierA: all LDS_A(k)/W(k) reads done
    __builtin_amdgcn_sched_barrier(0);
    // [W] ds_write A(k+1): compiler waits the gathers (younger than W-stage
    // in issue order -> W(k+1) drained implicitly; idx(k+2) stays in flight)
#pragma unroll
    for (int q = 0; q < 4; ++q) {
      int cA = q * 4 + jl;
      *(uint4*)(lds_raw + cA * 2048 + ((srow ^ (2 * cA)) << 4)) = ag[q];
    }
    asm volatile("s_waitcnt lgkmcnt(0)" ::: "memory");
    __builtin_amdgcn_sched_barrier(0);
    __builtin_amdgcn_s_barrier();                 // BarrierB: A(k+1)/W(k+1) ready
    __builtin_amdgcn_sched_barrier(0);
  }

  // ---- epilogue ----
  __syncthreads();                                // drain stray clamped W stage (k=26)

  // partner reduce: j=1 waves write partial accs to scratch; j=0 adds
  {
    float* scr = (float*)(lds_raw + 32768 + (size_t)(c_ * 2 + g) * 32768);
    if (j == 1) {
#pragma unroll
      for (int t = 0; t < 16; ++t) {
        float4 v0 = { acc0[t >> 2][(t & 3) * 4 + 0], acc0[t >> 2][(t & 3) * 4 + 1],
                      acc0[t >> 2][(t & 3) * 4 + 2], acc0[t >> 2][(t & 3) * 4 + 3] };
        float4 v1 = { acc1[t >> 2][(t & 3) * 4 + 0], acc1[t >> 2][(t & 3) * 4 + 1],
                      acc1[t >> 2][(t & 3) * 4 + 2], acc1[t >> 2][(t & 3) * 4 + 3] };
        *(float4*)(scr + (size_t)(t * 64 + lane) * 4) = v0;
        *(float4*)(scr + (size_t)((t + 16) * 64 + lane) * 4) = v1;
      }
    }
  }
  __syncthreads();
  if (j == 0) {
    float* scr = (float*)(lds_raw + 32768 + (size_t)(c_ * 2 + g) * 32768);
#pragma unroll
    for (int t = 0; t < 16; ++t) {
      float4 v0 = *(const float4*)(scr + (size_t)(t * 64 + lane) * 4);
      float4 v1 = *(const float4*)(scr + (size_t)((t + 16) * 64 + lane) * 4);
#pragma unroll
      for (int e = 0; e < 4; ++e) {
        acc0[t >> 2][(t & 3) * 4 + e] += ((const float*)&v0)[e];
        acc1[t >> 2][(t & 3) * 4 + e] += ((const float*)&v1)[e];
      }
    }
    // bias + relu
    const float* bb = c_ ? b2 : b1;
#pragma unroll
    for (int ct = 0; ct < 4; ++ct) {
      float bias = bb[ct * 32 + (lane & 31)];
#pragma unroll
      for (int r = 0; r < 16; ++r) {
        acc0[ct][r] = fmaxf(acc0[ct][r] + bias, 0.f);
        acc1[ct][r] = fmaxf(acc1[ct][r] + bias, 0.f);
      }
    }
  }

  int seg0 = segids[n0];
  bool uniform = (seg0 == segids[n0 + 127]);      // segment_ids are sorted

  // segment column sums of out2 (uniform fast path)
  if (c_ == 1 && j == 0 && uniform) {
#pragma unroll
    for (int ct = 0; ct < 4; ++ct) {
      float s = 0.f;
#pragma unroll
      for (int r = 0; r < 16; ++r) s += acc0[ct][r] + acc1[ct][r];
      s += __shfl_xor(s, 32);                     // combine h halves -> 64-row col sums
      if (lane < 32) atomicAdd(&seg_sums[seg0 * 128 + ct * 32 + lane], s);
    }
  }
  if (tid == 0 && uniform) atomicAdd(&cnts_f[seg0], 128.0f);

  __syncthreads();                                // scratch reads done before overwrite
  // transpose (j=0 waves) -> row-major f16 [2][128][128] at [0,64K)
  _Float16* lds_out = (_Float16*)lds_raw;
  if (j == 0) {
#pragma unroll
    for (int ct = 0; ct < 4; ++ct) {
      int col = ct * 32 + (lane & 31);
#pragma unroll
      for (int r = 0; r < 16; ++r) {
        int lr = g * 64 + (r & 3) + 8 * (r >> 2) + 4 * h;   // C/D row map (m74/m101)
        lds_out[c_ * 16384 + lr * 128 + col] = (_Float16)acc0[ct][r];
        lds_out[c_ * 16384 + (lr + 32) * 128 + col] = (_Float16)acc1[ct][r];
      }
    }
  }
  __syncthreads();

  if (!uniform && tid < 128) {                    // rare boundary blocks: per-row atomics
    int s = segids[n0 + tid];
    atomicAdd(&cnts_f[s], 1.0f);
    for (int c = 0; c < 128; ++c)
      atomicAdd(&seg_sums[s * 128 + c], (float)lds_out[16384 + tid * 128 + c]);
  }

  // coalesced row-major stores of out1/out2 (64KB total)
#pragma unroll
  for (int it = 0; it < 8; ++it) {
    int chunk = it * 512 + tid;                   // 0..4095, 16B each
    int cv = chunk >> 11;
    int off16 = chunk & 2047;
    uint4 v = *(const uint4*)(lds_raw + cv * 32768 + off16 * 16);
    *(uint4*)((cv ? out2 : out1) + (size_t)n0 * 128 + off16 * 8) = v;
  }
}

// ---------------- final kernel: enc/mid + mid@W3 + relu(feats - relu(.)) ----------------
__global__ __launch_bounds__(256, 2) void final_kernel(
    const float* __restrict__ feats, const _Float16* __restrict__ out1,
    const _Float16* __restrict__ out2, const int* __restrict__ segids,
    const float* __restrict__ seg_sums, const float* __restrict__ cnts_f,
    const char* __restrict__ pW3, const float* __restrict__ b3,
    float* __restrict__ dout) {
  __shared__ __align__(16) char ldsw3[32768];
  __shared__ float smean[NSEG * 128];
  int tid = threadIdx.x, w = tid >> 6, lane = tid & 63, h = lane >> 5;
  int n0 = blockIdx.x * 128;
#pragma unroll
  for (int it = 0; it < 8; ++it)
    load_lds16(pW3 + w * 8192 + it * 1024 + lane * 16, ldsw3 + w * 8192 + it * 1024);
  for (int i = tid; i < NSEG * 128; i += 256)
    smean[i] = seg_sums[i] / fmaxf(cnts_f[i >> 7], 1.0f);
  __syncthreads();

  int row = n0 + w * 32 + (lane & 31);
  int seg = segids[row];
  const char* p1 = (const char*)(out1 + (size_t)row * 128 + h * 8);
  const char* p2 = (const char*)(out2 + (size_t)row * 128 + h * 8);
  f16x8 o1[8], o2[8];
  float s1 = 0.f;
#pragma unroll
  for (int ko = 0; ko < 8; ++ko) {
    o1[ko] = *(const f16x8*)(p1 + ko * 32);
    o2[ko] = *(const f16x8*)(p2 + ko * 32);
#pragma unroll
    for (int j = 0; j < 8; ++j) s1 += (float)o1[ko][j];
  }
  s1 += __shfl_xor(s1, 32);
  float rm = s1 * (1.0f / 128.0f);             // row mean of out1 (out1 >= 0)

  f16x8 a[8];
#pragma unroll
  for (int ko = 0; ko < 8; ++ko) {
    int colb = ko * 16 + h * 8;
#pragma unroll
    for (int j = 0; j < 8; ++j) {
      float m2 = smean[seg * 128 + colb + j];
      float e = sqrtf(fmaf(rm, m2, 1e-12f));
      a[ko][j] = (_Float16)(e + (float)o1[ko][j] + (float)o2[ko][j]);
    }
  }
  floatx16 acc[4];
#pragma unroll
  for (int ct = 0; ct < 4; ++ct)
#pragma unroll
    for (int r = 0; r < 16; ++r) acc[ct][r] = 0.f;
#pragma unroll
  for (int ko = 0; ko < 8; ++ko)
#pragma unroll
    for (int ct = 0; ct < 4; ++ct) {
      f16x8 b = *(const f16x8*)(ldsw3 + ((ko * 4 + ct) * 64 + lane) * 16);
      acc[ct] = __builtin_amdgcn_mfma_f32_32x32x16_f16(a[ko], b, acc[ct], 0, 0, 0);
    }
#pragma unroll
  for (int ct = 0; ct < 4; ++ct) {
    int col = ct * 32 + (lane & 31);
    float bc = b3[col];
#pragma unroll
    for (int r = 0; r < 16; ++r) {
      int gr = n0 + w * 32 + (r & 3) + 8 * (r >> 2) + 4 * h;
      float v = fmaxf(acc[ct][r] + bc, 0.f);
      float f = feats[(size_t)gr * 128 + col];
      dout[(size_t)gr * 128 + col] = fmaxf(f - v, 0.f);
    }
  }
}

extern "C" void kernel_launch(void* const* d_in, const int* in_sizes, int n_in,
                              void* d_out, int out_size, void* d_ws, size_t ws_size,
                              hipStream_t stream) {
  (void)in_sizes; (void)n_in; (void)out_size; (void)ws_size;
  const float* feats = (const float*)d_in[0];
  const int* nidx   = (const int*)d_in[1];
  const int* nmask  = (const int*)d_in[2];   // bool mask; int32 per harness convention
  const int* segids = (const int*)d_in[3];
  const float* W1 = (const float*)d_in[5];
  const float* b1 = (const float*)d_in[6];
  const float* W2 = (const float*)d_in[7];
  const float* b2 = (const float*)d_in[8];
  const float* W3 = (const float*)d_in[9];
  const float* b3 = (const float*)d_in[10];
  float* dout = (float*)d_out;
  char* ws = (char*)d_ws;

  _Float16* featsh = (_Float16*)(ws + OFF_FEATSH);
  _Float16* out1h  = (_Float16*)(ws + OFF_OUT1);
  _Float16* out2h  = (_Float16*)(ws + OFF_OUT2);
  _Float16* pW1    = (_Float16*)(ws + OFF_PW1);
  _Float16* pW2    = (_Float16*)(ws + OFF_PW2);
  _Float16* pW3    = (_Float16*)(ws + OFF_PW3);
  float* seg_sums  = (float*)(ws + OFF_SEG);
  float* cnts_f    = (float*)(ws + OFF_CNT);

  // zero seg sums + counts + the masked-gather zero row (contiguous)
  hipMemsetAsync(ws + OFF_SEG, 0, 4096 + 32 + 256, stream);
  cvt_feats<<<25000, 256, 0, stream>>>(feats, featsh);
  pack_w<<<440, 256, 0, stream>>>(W1, W2, W3, pW1, pW2, pW3);
  conv_kernel<<<3125, 512, 0, stream>>>(featsh, nidx, nmask, segids, pW1, pW2,
                                        b1, b2, out1h, out2h, seg_sums, cnts_f);
  final_kernel<<<3125, 256, 0, stream>>>(feats, out1h, out2h, segids, seg_sums,
                                         cnts_f, (const char*)pW3, b3, dout);
}